// Round 1
// 605.657 us; speedup vs baseline: 1.1143x; 1.1143x over previous
//
#include <hip/hip_runtime.h>
#include <hip/hip_bf16.h>

// Problem shape (fixed by reference): x (2,4096,2048) f32, W (8192,2048) f32,
// bias (8192,) f32, out (2,4096,8192) f32.  GEMM: M=8192, N=8192, K=2048.
#define M_DIM 8192
#define N_DIM 8192
#define K_DIM 2048
#define BM 256
#define BN 256
#define BK 32
#define NT (K_DIM / BK)  // 64 K-tiles

typedef __attribute__((ext_vector_type(8))) short bf16x8;   // 8 bf16 in 4 VGPRs
typedef __attribute__((ext_vector_type(4))) float floatx4;  // MFMA C/D

__device__ __forceinline__ void gload_lds16(const void* g, void* l) {
  // global -> LDS direct DMA, 16 B per lane; LDS dest is wave-uniform base + lane*16
  __builtin_amdgcn_global_load_lds(
      (const __attribute__((address_space(1))) unsigned int*)g,
      (__attribute__((address_space(3))) unsigned int*)l, 16, 0, 0);
}

__device__ inline short f2bf(float f) {
  __hip_bfloat16 h = __float2bfloat16(f);  // RNE
  return *(short*)&h;
}

__device__ inline float round_bf16(float f) {
  __hip_bfloat16 h = __float2bfloat16(f);
  return __bfloat162float(h);
}

// ---------------- amax over BOTH tensors in one launch ----------------------
// blocks [0,1024): x -> bits[0]; blocks [1024,2048): w -> bits[1]
__global__ __launch_bounds__(256) void amax2_kernel(const float* __restrict__ x,
                                                    const float* __restrict__ w,
                                                    int n,
                                                    unsigned int* __restrict__ bits) {
  int b = blockIdx.x;
  const float* src;
  unsigned int* ob;
  if (b < 1024) { src = x; ob = bits + 0; } else { src = w; ob = bits + 1; b -= 1024; }
  int tid = threadIdx.x;
  int start = (b * 256 + tid) * 4;
  const int stride = 1024 * 256 * 4;
  float m = 0.0f;
  for (int i = start; i < n; i += stride) {
    float4 v = *(const float4*)(src + i);
    m = fmaxf(m, fmaxf(fmaxf(fabsf(v.x), fabsf(v.y)), fmaxf(fabsf(v.z), fabsf(v.w))));
  }
  for (int off = 32; off > 0; off >>= 1) m = fmaxf(m, __shfl_down(m, off));
  __shared__ float red[4];
  if ((tid & 63) == 0) red[tid >> 6] = m;
  __syncthreads();
  if (tid == 0) {
    m = fmaxf(fmaxf(red[0], red[1]), fmaxf(red[2], red[3]));
    atomicMax(ob, __float_as_uint(m));  // |x| >= 0: bit order == float order
  }
}

// ---------------- quantize BOTH tensors: dst = bf16(src / (amax/448)) -------
// blocks [0,8192): x -> xq; blocks [8192,16384): w -> wq
__global__ __launch_bounds__(256) void quant2_kernel(const float* __restrict__ x,
                                                     const float* __restrict__ w,
                                                     short* __restrict__ xq,
                                                     short* __restrict__ wq,
                                                     const unsigned int* __restrict__ bits) {
  int b = blockIdx.x;
  const float* src;
  short* dst;
  const unsigned int* ab;
  if (b < 8192) { src = x; dst = xq; ab = bits + 0; }
  else          { src = w; dst = wq; ab = bits + 1; b -= 8192; }
  float scale = __uint_as_float(*ab) / 448.0f;  // fp32 division, matches ref
  int idx = (b * 256 + threadIdx.x) * 8;
  float4 v0 = *(const float4*)(src + idx);
  float4 v1 = *(const float4*)(src + idx + 4);
  bf16x8 o;
  o[0] = f2bf(v0.x / scale);
  o[1] = f2bf(v0.y / scale);
  o[2] = f2bf(v0.z / scale);
  o[3] = f2bf(v0.w / scale);
  o[4] = f2bf(v1.x / scale);
  o[5] = f2bf(v1.y / scale);
  o[6] = f2bf(v1.z / scale);
  o[7] = f2bf(v1.w / scale);
  *(bf16x8*)(dst + idx) = o;
}

// ---------------- GEMM: C[m,n] = bf16(sum_k A[m,k]*B[n,k]) * s + bias[n] ----
// R3: 256x256 tile, 8 waves (2M x 4N), 512 threads, triple-buffered LDS
// pipeline with counted vmcnt (T3+T4), setprio around MFMA clusters (T5),
// proven chunk swizzle q ^ ((r>>1)&3) (T2, measured 0 bank conflicts in R1/R2),
// XCD-aware block swizzle (T1), non-temporal C stores (L3 thrash: R2 FETCH was
// 421 MB vs 67 MB unique input).
//
// Pipeline invariants (race-free by construction):
//  - compute tile t reads buf[t%3]; staging during tile t targets buf[(t+2)%3].
//  - buf[(t+2)%3] == buf[(t-1)%3]: its last reader finished before the final
//    barrier of tile t-1, which every wave crossed before issuing t+2 staging.
//  - end-of-tile checkpoint: s_waitcnt vmcnt(4) -> tile t+1's 4 loads (issued
//    during t-1) complete; tile t+2's 4 loads stay in flight across barriers.
//  - raw s_barrier (no implicit vmcnt/lgkm drain); lgkmcnt(0) after barrier
//    covers the phase's ds_reads (issued before the barrier).
// Per phase: {8|4 ds_read_b128, 2 global_load_lds, barrier, lgkmcnt(0),
//            setprio(1), 16 MFMA, setprio(0), [vmcnt], barrier}.
// Fragment construction / accumulation order identical to R2 -> bit-identical C.

template <int MODE>  // 0: stage t+2 + vmcnt(4); 1: no stage + vmcnt(0); 2: last tile
__device__ __forceinline__ void tile_body(
    short* lds, int cur, int nxt, int t,
    const short* aS0, const short* aS1, const short* bS0, const short* bS1,
    int tid, int rA, int rB, int ak, floatx4 (&acc)[8][4]) {
  short* sA = lds + cur * 16384;
  short* sB = sA + 8192;
  const int ko2 = (t + 2) * BK;

  bf16x8 a0[4], bfr[4], a1[4];
  // ---- phase 0: quadrant 0 (wave rows 0..63), full B frags ----
#pragma unroll
  for (int i = 0; i < 4; ++i)
    a0[i] = *(const bf16x8*)(sA + (rA + i * 16) * BK + ak);
#pragma unroll
  for (int j = 0; j < 4; ++j)
    bfr[j] = *(const bf16x8*)(sB + (rB + j * 16) * BK + ak);
  if constexpr (MODE == 0) {  // stage A-tile of t+2
    short* d = lds + nxt * 16384;
    gload_lds16(aS0 + ko2, d + tid * 8);
    gload_lds16(aS1 + ko2, d + 4096 + tid * 8);
  }
  __builtin_amdgcn_s_barrier();
  asm volatile("s_waitcnt lgkmcnt(0)" ::: "memory");
  __builtin_amdgcn_s_setprio(1);
#pragma unroll
  for (int i = 0; i < 4; ++i)
#pragma unroll
    for (int j = 0; j < 4; ++j)
      acc[i][j] = __builtin_amdgcn_mfma_f32_16x16x32_bf16(a0[i], bfr[j], acc[i][j], 0, 0, 0);
  __builtin_amdgcn_s_setprio(0);
  __builtin_amdgcn_s_barrier();

  // ---- phase 1: quadrant 1 (wave rows 64..127), reuse B frags ----
#pragma unroll
  for (int i = 0; i < 4; ++i)
    a1[i] = *(const bf16x8*)(sA + (rA + 64 + i * 16) * BK + ak);
  if constexpr (MODE == 0) {  // stage B-tile of t+2
    short* d = lds + nxt * 16384 + 8192;
    gload_lds16(bS0 + ko2, d + tid * 8);
    gload_lds16(bS1 + ko2, d + 4096 + tid * 8);
  }
  __builtin_amdgcn_s_barrier();
  asm volatile("s_waitcnt lgkmcnt(0)" ::: "memory");
  __builtin_amdgcn_s_setprio(1);
#pragma unroll
  for (int i = 0; i < 4; ++i)
#pragma unroll
    for (int j = 0; j < 4; ++j)
      acc[4 + i][j] = __builtin_amdgcn_mfma_f32_16x16x32_bf16(a1[i], bfr[j], acc[4 + i][j], 0, 0, 0);
  __builtin_amdgcn_s_setprio(0);
  if constexpr (MODE == 0)
    asm volatile("s_waitcnt vmcnt(4)" ::: "memory");  // t+1 resident; t+2 in flight
  else if constexpr (MODE == 1)
    asm volatile("s_waitcnt vmcnt(0)" ::: "memory");  // drain for final tile
  if constexpr (MODE != 2) __builtin_amdgcn_s_barrier();
}

__global__ __launch_bounds__(512, 2) void gemm_kernel(
    const short* __restrict__ A,   // Xq [M,K] bf16 bits
    const short* __restrict__ B,   // Wq [N,K] bf16 bits
    const float* __restrict__ bias,
    const unsigned int* __restrict__ amax_bits,  // [0]=x amax, [1]=w amax
    float* __restrict__ C) {
  // 3 buffers x (A 256x32 + B 256x32) bf16 = 3 x 32 KiB = 96 KiB
  __shared__ short lds[3 * 16384];

  const int tid = threadIdx.x;
  const int lane = tid & 63;
  const int waveId = tid >> 6;
  const int waveM = waveId >> 2;  // 0..1
  const int waveN = waveId & 3;   // 0..3

  // XCD-aware bijective swizzle: nwg=1024, 8 XCDs -> each XCD owns a
  // contiguous chunk of 128 tiles (4 grid rows) for A-panel L2 reuse.
  int bid = blockIdx.y * 32 + blockIdx.x;
  bid = (bid & 7) * 128 + (bid >> 3);
  const int m0 = (bid >> 5) * BM;
  const int n0 = (bid & 31) * BN;

  // Staging: tile = 256 rows x 32 bf16 per matrix = 1024 chunks of 16 B.
  // Thread t fills chunks t (rows 0..127) and t+512 (rows 128..255).
  // Physical chunk pc of row r holds logical chunk pc ^ ((r>>1)&3); the DMA
  // dest must stay lane*16-linear, so the swizzle is applied to the *source*
  // address. Rows r and r+128 share the same q0 ((r>>1)&3 has period 8).
  const int r0 = tid >> 2;
  const int q0 = (tid & 3) ^ ((tid >> 3) & 3);
  const short* aS0 = A + (long)(m0 + r0) * K_DIM + q0 * 8;
  const short* aS1 = aS0 + (long)128 * K_DIM;
  const short* bS0 = B + (long)(n0 + r0) * K_DIM + q0 * 8;
  const short* bS1 = bS0 + (long)128 * K_DIM;

  // Fragment read: row = base + (lane&15), logical chunk c = lane>>4,
  // physical chunk = c ^ ((row>>1)&3) = c ^ ((lane>>1)&3)  (bases %16 == 0).
  const int rA = waveM * 128 + (lane & 15);  // + qd*64 + i*16
  const int rB = waveN * 64 + (lane & 15);   // + j*16
  const int ak = ((lane >> 4) ^ ((lane >> 1) & 3)) * 8;

  floatx4 acc[8][4] = {};

  // Prologue: stage tile 0 -> buf0, tile 1 -> buf1; wait tile 0 (4 of 8 loads).
  {
    short* d0 = lds;
    gload_lds16(aS0, d0 + tid * 8);
    gload_lds16(aS1, d0 + 4096 + tid * 8);
    gload_lds16(bS0, d0 + 8192 + tid * 8);
    gload_lds16(bS1, d0 + 8192 + 4096 + tid * 8);
    short* d1 = lds + 16384;
    gload_lds16(aS0 + BK, d1 + tid * 8);
    gload_lds16(aS1 + BK, d1 + 4096 + tid * 8);
    gload_lds16(bS0 + BK, d1 + 8192 + tid * 8);
    gload_lds16(bS1 + BK, d1 + 8192 + 4096 + tid * 8);
  }
  asm volatile("s_waitcnt vmcnt(4)" ::: "memory");
  __builtin_amdgcn_s_barrier();

  // Main loop: 60 tiles in groups of 3 (buffer rotation is compile-time),
  // then tiles 60,61 (still staging 62,63), then drain tiles 62,63.
#pragma unroll 1
  for (int tt = 0; tt < 60; tt += 3) {
    tile_body<0>(lds, 0, 2, tt,     aS0, aS1, bS0, bS1, tid, rA, rB, ak, acc);
    tile_body<0>(lds, 1, 0, tt + 1, aS0, aS1, bS0, bS1, tid, rA, rB, ak, acc);
    tile_body<0>(lds, 2, 1, tt + 2, aS0, aS1, bS0, bS1, tid, rA, rB, ak, acc);
  }
  tile_body<0>(lds, 0, 2, 60, aS0, aS1, bS0, bS1, tid, rA, rB, ak, acc);
  tile_body<0>(lds, 1, 0, 61, aS0, aS1, bS0, bS1, tid, rA, rB, ak, acc);
  tile_body<1>(lds, 2, 0, 62, aS0, aS1, bS0, bS1, tid, rA, rB, ak, acc);
  tile_body<2>(lds, 0, 0, 63, aS0, aS1, bS0, bS1, tid, rA, rB, ak, acc);

  // Epilogue: ref = bf16(einsum).astype(f32) * (w_scale*x_scale) + bias.
  // Non-temporal stores: C is write-once; keep A/B resident in L2/L3.
  const float sx = __uint_as_float(amax_bits[0]) / 448.0f;
  const float sw = __uint_as_float(amax_bits[1]) / 448.0f;
  const float s = sx * sw;
  const int col = lane & 15;
  const int rq = (lane >> 4) * 4;  // C/D: row = (lane>>4)*4 + reg, col = lane&15
#pragma unroll
  for (int j = 0; j < 4; ++j) {
    const int n = n0 + waveN * 64 + j * 16 + col;
    const float bv = bias[n];
#pragma unroll
    for (int fi = 0; fi < 8; ++fi) {
      const int mBase = m0 + waveM * 128 + fi * 16 + rq;
#pragma unroll
      for (int r = 0; r < 4; ++r) {
        float v = round_bf16(acc[fi][j][r]);  // match XLA bf16 dot output demote
        __builtin_nontemporal_store(v * s + bv, &C[(long)(mBase + r) * N_DIM + n]);
      }
    }
  }
}

extern "C" void kernel_launch(void* const* d_in, const int* in_sizes, int n_in,
                              void* d_out, int out_size, void* d_ws, size_t ws_size,
                              hipStream_t stream) {
  const float* x = (const float*)d_in[0];     // (2,4096,2048)
  const float* w = (const float*)d_in[1];     // (8192,2048)
  const float* bias = (const float*)d_in[2];  // (8192,)
  float* out = (float*)d_out;

  // Workspace layout: [0..63] amax bits (u32[0]=x, u32[1]=w); then Xq; then Wq.
  unsigned int* bits = (unsigned int*)d_ws;
  short* xq = (short*)((char*)d_ws + 256);
  short* wq = (short*)((char*)d_ws + 256 + (size_t)M_DIM * K_DIM * sizeof(short));

  hipMemsetAsync(d_ws, 0, 64, stream);  // zero amax slots (ws is poisoned 0xAA)

  amax2_kernel<<<2048, 256, 0, stream>>>(x, w, M_DIM * K_DIM, bits);
  quant2_kernel<<<16384, 256, 0, stream>>>(x, w, xq, wq, bits);
  gemm_kernel<<<dim3(N_DIM / BN, M_DIM / BM), 512, 0, stream>>>(xq, wq, bias, bits, out);
}

// Round 2
// 592.854 us; speedup vs baseline: 1.1383x; 1.0216x over previous
//
#include <hip/hip_runtime.h>
#include <hip/hip_bf16.h>

// Problem shape (fixed by reference): x (2,4096,2048) f32, W (8192,2048) f32,
// bias (8192,) f32, out (2,4096,8192) f32.  GEMM: M=8192, N=8192, K=2048.
#define M_DIM 8192
#define N_DIM 8192
#define K_DIM 2048
#define BM 256
#define BN 256
#define BK 32

typedef __attribute__((ext_vector_type(8))) short bf16x8;   // 8 bf16 in 4 VGPRs
typedef __attribute__((ext_vector_type(4))) float floatx4;  // MFMA C/D, also f32x4 stores

__device__ __forceinline__ void gload_lds16(const void* g, void* l) {
  // global -> LDS direct DMA, 16 B per lane; LDS dest is wave-uniform base + lane*16
  __builtin_amdgcn_global_load_lds(
      (const __attribute__((address_space(1))) unsigned int*)g,
      (__attribute__((address_space(3))) unsigned int*)l, 16, 0, 0);
}

__device__ inline short f2bf(float f) {
  __hip_bfloat16 h = __float2bfloat16(f);  // RNE
  return *(short*)&h;
}

__device__ inline float round_bf16(float f) {
  __hip_bfloat16 h = __float2bfloat16(f);
  return __bfloat162float(h);
}

// ---------------- amax over BOTH tensors in one launch ----------------------
// blocks [0,1024): x -> bits[0]; blocks [1024,2048): w -> bits[1]
__global__ __launch_bounds__(256) void amax2_kernel(const float* __restrict__ x,
                                                    const float* __restrict__ w,
                                                    int n,
                                                    unsigned int* __restrict__ bits) {
  int b = blockIdx.x;
  const float* src;
  unsigned int* ob;
  if (b < 1024) { src = x; ob = bits + 0; } else { src = w; ob = bits + 1; b -= 1024; }
  int tid = threadIdx.x;
  int start = (b * 256 + tid) * 4;
  const int stride = 1024 * 256 * 4;
  float m = 0.0f;
  for (int i = start; i < n; i += stride) {
    float4 v = *(const float4*)(src + i);
    m = fmaxf(m, fmaxf(fmaxf(fabsf(v.x), fabsf(v.y)), fmaxf(fabsf(v.z), fabsf(v.w))));
  }
  for (int off = 32; off > 0; off >>= 1) m = fmaxf(m, __shfl_down(m, off));
  __shared__ float red[4];
  if ((tid & 63) == 0) red[tid >> 6] = m;
  __syncthreads();
  if (tid == 0) {
    m = fmaxf(fmaxf(red[0], red[1]), fmaxf(red[2], red[3]));
    atomicMax(ob, __float_as_uint(m));  // |x| >= 0: bit order == float order
  }
}

// ---------------- quantize BOTH tensors: dst = bf16(src / (amax/448)) -------
// blocks [0,8192): x -> xq; blocks [8192,16384): w -> wq
__global__ __launch_bounds__(256) void quant2_kernel(const float* __restrict__ x,
                                                     const float* __restrict__ w,
                                                     short* __restrict__ xq,
                                                     short* __restrict__ wq,
                                                     const unsigned int* __restrict__ bits) {
  int b = blockIdx.x;
  const float* src;
  short* dst;
  const unsigned int* ab;
  if (b < 8192) { src = x; dst = xq; ab = bits + 0; }
  else          { src = w; dst = wq; ab = bits + 1; b -= 8192; }
  float scale = __uint_as_float(*ab) / 448.0f;  // fp32 division, matches ref
  int idx = (b * 256 + threadIdx.x) * 8;
  float4 v0 = *(const float4*)(src + idx);
  float4 v1 = *(const float4*)(src + idx + 4);
  bf16x8 o;
  o[0] = f2bf(v0.x / scale);
  o[1] = f2bf(v0.y / scale);
  o[2] = f2bf(v0.z / scale);
  o[3] = f2bf(v0.w / scale);
  o[4] = f2bf(v1.x / scale);
  o[5] = f2bf(v1.y / scale);
  o[6] = f2bf(v1.z / scale);
  o[7] = f2bf(v1.w / scale);
  *(bf16x8*)(dst + idx) = o;
}

// ---------------- GEMM: C[m,n] = bf16(sum_k A[m,k]*B[n,k]) * s + bias[n] ----
// R4: 256x256 tile, 8 waves (2M x 4N), 512 threads, triple-buffered LDS
// pipeline with counted vmcnt (T3+T4), setprio (T5), chunk swizzle (T2,
// measured 0 conflicts), XCD swizzle (T1).
// R4 changes vs R3 (276 us, MfmaUtil 44.7, FETCH 541 MB):
//  (a) removed explicit lgkmcnt(0) before MFMA clusters -- the ds_reads are
//      compiler-visible loads, so hipcc emits fine-grained lgkmcnt(N) and the
//      first MFMA starts after the first fragment lands instead of after a
//      full 8-12 read drain.
//  (b) staging gloads issue BEFORE the phase's ds_reads (earlier VMEM issue).
//  (c) epilogue: per-wave LDS transpose -> full-128-B-line nontemporal float4
//      stores. R3's scalar nt stores were 64-B half-lines -> memory-side RMW
//      (the +270 MB phantom FETCH).
//
// Pipeline invariants (race-free by construction):
//  - compute tile t reads buf[t%3]; staging during tile t targets buf[(t+2)%3]
//    == buf[(t-1)%3], whose last reader finished before the end-of-(t-1)
//    barrier that every wave crossed before issuing t+2 staging.
//  - end-of-tile checkpoint s_waitcnt vmcnt(4): each wave's 4 loads for t+1
//    (issued during t-1) are complete; t+2's 4 stay in flight across barriers.
//    All waves pass their own vmcnt(4) before the barrier, and every wave
//    stages its own LDS slice, so after the barrier buf[t+1] is fully
//    resident.
//  - raw s_barrier (no implicit vmcnt/lgkm drain).

template <int MODE>  // 0: stage t+2 + vmcnt(4); 1: no stage + vmcnt(0); 2: last tile
__device__ __forceinline__ void tile_body(
    short* lds, int cur, int nxt, int t,
    const short* aS0, const short* aS1, const short* bS0, const short* bS1,
    int tid, int rA, int rB, int ak, floatx4 (&acc)[8][4]) {
  short* sA = lds + cur * 16384;
  short* sB = sA + 8192;
  const int ko2 = (t + 2) * BK;

  bf16x8 a0[4], bfr[4], a1[4];
  // ---- phase 0: quadrant 0 (wave rows 0..63), full B frags ----
  if constexpr (MODE == 0) {  // stage A-tile of t+2 (issue before ds_reads)
    short* d = lds + nxt * 16384;
    gload_lds16(aS0 + ko2, d + tid * 8);
    gload_lds16(aS1 + ko2, d + 4096 + tid * 8);
  }
#pragma unroll
  for (int i = 0; i < 4; ++i)
    a0[i] = *(const bf16x8*)(sA + (rA + i * 16) * BK + ak);
#pragma unroll
  for (int j = 0; j < 4; ++j)
    bfr[j] = *(const bf16x8*)(sB + (rB + j * 16) * BK + ak);
  __builtin_amdgcn_s_barrier();
  __builtin_amdgcn_s_setprio(1);
#pragma unroll
  for (int i = 0; i < 4; ++i)
#pragma unroll
    for (int j = 0; j < 4; ++j)
      acc[i][j] = __builtin_amdgcn_mfma_f32_16x16x32_bf16(a0[i], bfr[j], acc[i][j], 0, 0, 0);
  __builtin_amdgcn_s_setprio(0);
  __builtin_amdgcn_s_barrier();

  // ---- phase 1: quadrant 1 (wave rows 64..127), reuse B frags ----
  if constexpr (MODE == 0) {  // stage B-tile of t+2
    short* d = lds + nxt * 16384 + 8192;
    gload_lds16(bS0 + ko2, d + tid * 8);
    gload_lds16(bS1 + ko2, d + 4096 + tid * 8);
  }
#pragma unroll
  for (int i = 0; i < 4; ++i)
    a1[i] = *(const bf16x8*)(sA + (rA + 64 + i * 16) * BK + ak);
  __builtin_amdgcn_s_barrier();
  __builtin_amdgcn_s_setprio(1);
#pragma unroll
  for (int i = 0; i < 4; ++i)
#pragma unroll
    for (int j = 0; j < 4; ++j)
      acc[4 + i][j] = __builtin_amdgcn_mfma_f32_16x16x32_bf16(a1[i], bfr[j], acc[4 + i][j], 0, 0, 0);
  __builtin_amdgcn_s_setprio(0);
  if constexpr (MODE == 0)
    asm volatile("s_waitcnt vmcnt(4)" ::: "memory");  // t+1 resident; t+2 in flight
  else if constexpr (MODE == 1)
    asm volatile("s_waitcnt vmcnt(0)" ::: "memory");  // drain for final tile
  if constexpr (MODE != 2) __builtin_amdgcn_s_barrier();
}

__global__ __launch_bounds__(512, 2) void gemm_kernel(
    const short* __restrict__ A,   // Xq [M,K] bf16 bits
    const short* __restrict__ B,   // Wq [N,K] bf16 bits
    const float* __restrict__ bias,
    const unsigned int* __restrict__ amax_bits,  // [0]=x amax, [1]=w amax
    float* __restrict__ C) {
  // 3 buffers x (A 256x32 + B 256x32) bf16 = 3 x 32 KiB = 96 KiB
  __shared__ short lds[3 * 16384];

  const int tid = threadIdx.x;
  const int lane = tid & 63;
  const int waveId = tid >> 6;
  const int waveM = waveId >> 2;  // 0..1
  const int waveN = waveId & 3;   // 0..3

  // XCD-aware bijective swizzle: nwg=1024, 8 XCDs -> each XCD owns a
  // contiguous chunk of 128 tiles (4 grid rows) for A-panel L2 reuse.
  int bid = blockIdx.y * 32 + blockIdx.x;
  bid = (bid & 7) * 128 + (bid >> 3);
  const int m0 = (bid >> 5) * BM;
  const int n0 = (bid & 31) * BN;

  // Staging: tile = 256 rows x 32 bf16 per matrix = 1024 chunks of 16 B.
  // Thread t fills chunks t (rows 0..127) and t+512 (rows 128..255).
  // Physical chunk pc of row r holds logical chunk pc ^ ((r>>1)&3); the DMA
  // dest must stay lane*16-linear, so the swizzle is applied to the *source*
  // address. Rows r and r+128 share the same q0 ((r>>1)&3 has period 8).
  const int r0 = tid >> 2;
  const int q0 = (tid & 3) ^ ((tid >> 3) & 3);
  const short* aS0 = A + (long)(m0 + r0) * K_DIM + q0 * 8;
  const short* aS1 = aS0 + (long)128 * K_DIM;
  const short* bS0 = B + (long)(n0 + r0) * K_DIM + q0 * 8;
  const short* bS1 = bS0 + (long)128 * K_DIM;

  // Fragment read: row = base + (lane&15), logical chunk c = lane>>4,
  // physical chunk = c ^ ((row>>1)&3) = c ^ ((lane>>1)&3)  (bases %16 == 0).
  const int rA = waveM * 128 + (lane & 15);  // + qd*64 + i*16
  const int rB = waveN * 64 + (lane & 15);   // + j*16
  const int ak = ((lane >> 4) ^ ((lane >> 1) & 3)) * 8;

  floatx4 acc[8][4] = {};

  // Prologue: stage tile 0 -> buf0, tile 1 -> buf1; wait tile 0 (4 of 8 loads).
  {
    short* d0 = lds;
    gload_lds16(aS0, d0 + tid * 8);
    gload_lds16(aS1, d0 + 4096 + tid * 8);
    gload_lds16(bS0, d0 + 8192 + tid * 8);
    gload_lds16(bS1, d0 + 8192 + 4096 + tid * 8);
    short* d1 = lds + 16384;
    gload_lds16(aS0 + BK, d1 + tid * 8);
    gload_lds16(aS1 + BK, d1 + 4096 + tid * 8);
    gload_lds16(bS0 + BK, d1 + 8192 + tid * 8);
    gload_lds16(bS1 + BK, d1 + 8192 + 4096 + tid * 8);
  }
  asm volatile("s_waitcnt vmcnt(4)" ::: "memory");
  __builtin_amdgcn_s_barrier();

  // Main loop: 60 tiles in groups of 3 (buffer rotation is compile-time),
  // then tiles 60,61 (still staging 62,63), then drain tiles 62,63.
#pragma unroll 1
  for (int tt = 0; tt < 60; tt += 3) {
    tile_body<0>(lds, 0, 2, tt,     aS0, aS1, bS0, bS1, tid, rA, rB, ak, acc);
    tile_body<0>(lds, 1, 0, tt + 1, aS0, aS1, bS0, bS1, tid, rA, rB, ak, acc);
    tile_body<0>(lds, 2, 1, tt + 2, aS0, aS1, bS0, bS1, tid, rA, rB, ak, acc);
  }
  tile_body<0>(lds, 0, 2, 60, aS0, aS1, bS0, bS1, tid, rA, rB, ak, acc);
  tile_body<0>(lds, 1, 0, 61, aS0, aS1, bS0, bS1, tid, rA, rB, ak, acc);
  tile_body<1>(lds, 2, 0, 62, aS0, aS1, bS0, bS1, tid, rA, rB, ak, acc);
  tile_body<2>(lds, 0, 0, 63, aS0, aS1, bS0, bS1, tid, rA, rB, ak, acc);

  // Epilogue: ref = bf16(einsum).astype(f32) * (w_scale*x_scale) + bias.
  // Per-wave LDS transpose -> full-128-B-line nontemporal float4 stores.
  // Scratch: per wave 2 slots x 16 rows x 36 f32 (pad 4 keeps 16-B alignment,
  // spreads banks 2-way = free). 8 waves x 4608 B = 36 KiB, reuses `lds`.
  __syncthreads();  // all waves done reading tile buffers
  const float sx = __uint_as_float(amax_bits[0]) / 448.0f;
  const float sw = __uint_as_float(amax_bits[1]) / 448.0f;
  const float s = sx * sw;
  float* scr = (float*)lds + waveId * 1152;
  const int col = lane & 15;
  const int rq = (lane >> 4) * 4;   // acc C/D: row=(lane>>4)*4+r, col=lane&15
  const int rdRow = lane >> 3;      // 0..7
  const int rdCol = (lane & 7) * 4; // 0..28 step 4
#pragma unroll
  for (int jp = 0; jp < 2; ++jp) {
    const int nBase = n0 + waveN * 64 + jp * 32;  // 128-B aligned column group
    const float bv0 = bias[nBase + col];
    const float bv1 = bias[nBase + 16 + col];
#pragma unroll
    for (int fi = 0; fi < 8; ++fi) {
      float* sc = scr + (fi & 1) * 576;  // 2-slot rotation for wave-local overlap
#pragma unroll
      for (int r = 0; r < 4; ++r) {
        sc[(rq + r) * 36 + col]      = round_bf16(acc[fi][jp * 2][r]) * s + bv0;
        sc[(rq + r) * 36 + col + 16] = round_bf16(acc[fi][jp * 2 + 1][r]) * s + bv1;
      }
      const int mRow = m0 + waveM * 128 + fi * 16;
#pragma unroll
      for (int v = 0; v < 2; ++v) {
        floatx4 o = *(const floatx4*)(sc + (v * 8 + rdRow) * 36 + rdCol);
        __builtin_nontemporal_store(
            o, (floatx4*)&C[(long)(mRow + v * 8 + rdRow) * N_DIM + nBase + rdCol]);
      }
    }
  }
}

extern "C" void kernel_launch(void* const* d_in, const int* in_sizes, int n_in,
                              void* d_out, int out_size, void* d_ws, size_t ws_size,
                              hipStream_t stream) {
  const float* x = (const float*)d_in[0];     // (2,4096,2048)
  const float* w = (const float*)d_in[1];     // (8192,2048)
  const float* bias = (const float*)d_in[2];  // (8192,)
  float* out = (float*)d_out;

  // Workspace layout: [0..63] amax bits (u32[0]=x, u32[1]=w); then Xq; then Wq.
  unsigned int* bits = (unsigned int*)d_ws;
  short* xq = (short*)((char*)d_ws + 256);
  short* wq = (short*)((char*)d_ws + 256 + (size_t)M_DIM * K_DIM * sizeof(short));

  hipMemsetAsync(d_ws, 0, 64, stream);  // zero amax slots (ws is poisoned 0xAA)

  amax2_kernel<<<2048, 256, 0, stream>>>(x, w, M_DIM * K_DIM, bits);
  quant2_kernel<<<16384, 256, 0, stream>>>(x, w, xq, wq, bits);
  gemm_kernel<<<dim3(N_DIM / BN, M_DIM / BM), 512, 0, stream>>>(xq, wq, bias, bits, out);
}